// Round 4
// baseline (289.081 us; speedup 1.0000x reference)
//
#include <hip/hip_runtime.h>

typedef __bf16 bf16;
typedef __bf16 bf16x4 __attribute__((ext_vector_type(4)));
typedef __bf16 bf16x8 __attribute__((ext_vector_type(8)));
typedef float f32x4 __attribute__((ext_vector_type(4)));

#define NROWS 32768   // B*S = 32*1024
#define EMBED 512
#define CONV_C 512
#define HID 1024
#define LABELS 128

__device__ inline void async16(const void* g, void* l) {
  __builtin_amdgcn_global_load_lds(
      (const __attribute__((address_space(1))) void*)g,
      (__attribute__((address_space(3))) void*)l, 16, 0, 0);
}

// two 16B fp32 chunks (swizzled positions) -> bf16x8 fragment
__device__ inline bf16x8 cvt8_sw(const float* row, int o0, int o1) {
  f32x4 lo = *(const f32x4*)(row + o0);
  f32x4 hi = *(const f32x4*)(row + o1);
  bf16x8 r;
  r[0] = (bf16)lo[0]; r[1] = (bf16)lo[1]; r[2] = (bf16)lo[2]; r[3] = (bf16)lo[3];
  r[4] = (bf16)hi[0]; r[5] = (bf16)hi[1]; r[6] = (bf16)hi[2]; r[7] = (bf16)hi[3];
  return r;
}

// ---- prep kernels ----------------------------------------------------------

__global__ void cvt_bf16(const float* __restrict__ in, bf16* __restrict__ out, int n) {
  int i = (blockIdx.x * blockDim.x + threadIdx.x) * 4;
  if (i >= n) return;
  float4 v = *(const float4*)(in + i);
  bf16x4 o;
  o.x = (bf16)v.x; o.y = (bf16)v.y; o.z = (bf16)v.z; o.w = (bf16)v.w;
  *(bf16x4*)(out + i) = o;
}

// [K,N] f32 -> [N,K] bf16 transpose, 64x64 tiles
__global__ void transpose_cvt(const float* __restrict__ in, bf16* __restrict__ out,
                              int K, int N) {
  __shared__ float t[64][65];
  int kb = blockIdx.x * 64, nb = blockIdx.y * 64;
  for (int i = threadIdx.x; i < 4096; i += 256) {
    int r = i >> 6, c = i & 63;
    t[r][c] = in[(size_t)(kb + r) * N + nb + c];
  }
  __syncthreads();
  for (int i = threadIdx.x; i < 4096; i += 256) {
    int r = i >> 6, c = i & 63;
    out[(size_t)(nb + r) * K + kb + c] = (bf16)t[c][r];
  }
}

// ---- layer 1: h = relu(emb[tok] @ conv_w^T + conv_b), gather fused ---------
// 1-D grid, XCD-grouped: the 4 n-blocks of one m-slab run consecutively on
// one XCD so the gathered emb rows stay in that XCD's L2.
__global__ __launch_bounds__(256) void gemm1_gather(
    const int* __restrict__ tok, const float* __restrict__ emb,
    const bf16* __restrict__ convw, const float* __restrict__ bias,
    bf16* __restrict__ out, int M, int N, int K) {
  __shared__ __attribute__((aligned(16))) float lAf[128 * 32];  // 16 KB
  __shared__ __attribute__((aligned(16))) bf16 lB[128 * 32];    //  8 KB
  const int tid = threadIdx.x;
  const int wave = tid >> 6, lane = tid & 63;
  // XCD-aware decode: xcd = id&7 owns m-blocks == xcd (mod 8), n fastest
  const int id = blockIdx.x;
  const int xcd = id & 7, q = id >> 3;
  const int nb = q & 3, mb = (q >> 2) * 8 + xcd;
  const int m0 = mb * 128, n0 = nb * 128;
  const int wm = (wave & 1) * 64, wn = (wave >> 1) * 64;
  const int lrow = lane & 15, quad = lane >> 4;
  const int slot0 = wave * 64 + lane;

  int arow[4], acol[4];
#pragma unroll
  for (int c = 0; c < 4; ++c) {
    int s = slot0 + c * 256;
    int r = s >> 3, p = s & 7;
    arow[c] = r;
    acol[c] = (p ^ (r & 7)) * 4;  // swizzled source column (floats)
  }
  int trow[4];
#pragma unroll
  for (int c = 0; c < 4; ++c) trow[c] = tok[m0 + arow[c]];

  const f32x4 zero4 = {0.f, 0.f, 0.f, 0.f};
  f32x4 acc[4][4];
#pragma unroll
  for (int i = 0; i < 4; ++i)
#pragma unroll
    for (int j = 0; j < 4; ++j) acc[i][j] = zero4;

  for (int k0 = 0; k0 < K; k0 += 32) {
#pragma unroll
    for (int c = 0; c < 4; ++c)
      async16(emb + (size_t)trow[c] * EMBED + k0 + acol[c],
              lAf + (size_t)(wave * 64 + c * 256) * 4);
#pragma unroll
    for (int c = 0; c < 2; ++c) {
      int s = slot0 + c * 256;
      int r = s >> 2, cs = s & 3;
      async16(convw + (size_t)(n0 + r) * K + k0 + cs * 8,
              lB + (size_t)(wave * 64 + c * 256) * 8);
    }
    __syncthreads();

    bf16x8 a[4], b[4];
#pragma unroll
    for (int t = 0; t < 4; ++t) {
      int r = wm + t * 16 + lrow, sw = r & 7;
      a[t] = cvt8_sw(lAf + r * 32, ((2 * quad) ^ sw) * 4, ((2 * quad + 1) ^ sw) * 4);
      b[t] = *(const bf16x8*)(lB + (wn + t * 16 + lrow) * 32 + quad * 8);
    }
#pragma unroll
    for (int mi = 0; mi < 4; ++mi)
#pragma unroll
      for (int ni = 0; ni < 4; ++ni)
        acc[mi][ni] =
            __builtin_amdgcn_mfma_f32_16x16x32_bf16(a[mi], b[ni], acc[mi][ni], 0, 0, 0);
    __syncthreads();
  }

#pragma unroll
  for (int mi = 0; mi < 4; ++mi) {
#pragma unroll
    for (int ni = 0; ni < 4; ++ni) {
      int col = n0 + wn + ni * 16 + lrow;
      float bv = bias[col];
#pragma unroll
      for (int r = 0; r < 4; ++r) {
        int row = m0 + wm + mi * 16 + quad * 4 + r;
        float v = acc[mi][ni][r] + bv;
        v = v > 0.f ? v : 0.f;
        out[(size_t)row * N + col] = (bf16)v;
      }
    }
  }
}

// ---- fused layers 2+3 ------------------------------------------------------
// Per block: 64 rows. Loop over 8 hid-chunks of 128:
//   z_chunk = relu(h_rows @ w1t[chunk]^T + b1[chunk])      (K=512 MFMA)
//   out_acc += z_chunk @ w2t[:, chunk]^T                   (K=128 MFMA)
// z_chunk goes C-layout regs -> swizzled LDS -> A-layout frags (m120 pattern).
// out [64,128] f32 written once at the end with b2.
__global__ __launch_bounds__(256) void gemm23_fused(
    const bf16* __restrict__ h,     // [32768, 512]
    const bf16* __restrict__ w1t,   // [1024, 512]
    const bf16* __restrict__ w2t,   // [128, 1024]
    const float* __restrict__ b1, const float* __restrict__ b2,
    float* __restrict__ out) {
  __shared__ __attribute__((aligned(16))) bf16 lA[64 * 32];     //  4 KB
  __shared__ __attribute__((aligned(16))) bf16 lB[128 * 32];    //  8 KB
  __shared__ __attribute__((aligned(16))) bf16 zbuf[64 * 128];  // 16 KB swizzled
  __shared__ __attribute__((aligned(16))) bf16 lB3[128 * 128];  // 32 KB swizzled
  const int tid = threadIdx.x, wave = tid >> 6, lane = tid & 63;
  const int m0 = blockIdx.x * 64;
  const int wm = (wave & 1) * 32, wn = (wave >> 1) * 64;
  const int lrow = lane & 15, quad = lane >> 4;
  const int slot0 = wave * 64 + lane;

  const f32x4 zero4 = {0.f, 0.f, 0.f, 0.f};
  f32x4 out_acc[2][4];
#pragma unroll
  for (int i = 0; i < 2; ++i)
#pragma unroll
    for (int j = 0; j < 4; ++j) out_acc[i][j] = zero4;

  for (int chunk = 0; chunk < 8; ++chunk) {
    f32x4 z_acc[2][4];
#pragma unroll
    for (int i = 0; i < 2; ++i)
#pragma unroll
      for (int j = 0; j < 4; ++j) z_acc[i][j] = zero4;

    const bf16* wB = w1t + (size_t)(chunk * 128) * 512;
    for (int k0 = 0; k0 < 512; k0 += 32) {
      {  // A: 64 rows x 4 granules = 256 slots, 1 issue
        int r = slot0 >> 2, cs = slot0 & 3;
        async16(h + (size_t)(m0 + r) * 512 + k0 + cs * 8,
                lA + (size_t)(wave * 64) * 8);
      }
#pragma unroll
      for (int c = 0; c < 2; ++c) {  // B: 128 rows x 4 = 512 slots
        int g = slot0 + c * 256;
        int r = g >> 2, cs = g & 3;
        async16(wB + (size_t)r * 512 + k0 + cs * 8,
                lB + (size_t)(wave * 64 + c * 256) * 8);
      }
      __syncthreads();

      bf16x8 a[2], b[4];
#pragma unroll
      for (int t = 0; t < 2; ++t)
        a[t] = *(const bf16x8*)(lA + (wm + t * 16 + lrow) * 32 + quad * 8);
#pragma unroll
      for (int t = 0; t < 4; ++t)
        b[t] = *(const bf16x8*)(lB + (wn + t * 16 + lrow) * 32 + quad * 8);
#pragma unroll
      for (int mi = 0; mi < 2; ++mi)
#pragma unroll
        for (int ni = 0; ni < 4; ++ni)
          z_acc[mi][ni] =
              __builtin_amdgcn_mfma_f32_16x16x32_bf16(a[mi], b[ni], z_acc[mi][ni], 0, 0, 0);
      __syncthreads();
    }

    // stage w2t chunk into lB3 (granule-swizzled: slot p holds src granule p^(r&7))
#pragma unroll
    for (int c = 0; c < 8; ++c) {
      int s = slot0 + c * 256;
      int r = s >> 4, p = s & 15;
      int qs = p ^ (r & 7);
      async16(w2t + (size_t)r * HID + chunk * 128 + qs * 8,
              lB3 + (size_t)(wave * 64 + c * 256) * 8);
    }
    // write z (bias+relu, bf16) into swizzled zbuf
#pragma unroll
    for (int mi = 0; mi < 2; ++mi) {
#pragma unroll
      for (int ni = 0; ni < 4; ++ni) {
        int col = wn + ni * 16 + lrow;
        float bv = b1[chunk * 128 + col];
#pragma unroll
        for (int r = 0; r < 4; ++r) {
          int row = wm + mi * 16 + quad * 4 + r;
          float v = z_acc[mi][ni][r] + bv;
          v = v > 0.f ? v : 0.f;
          int g = col >> 3, wd = col & 7;
          int pos = g ^ (row & 7);
          zbuf[row * 128 + pos * 8 + wd] = (bf16)v;
        }
      }
    }
    __syncthreads();

    // layer 3: out_acc += z_chunk @ w2t_chunk^T (K=128)
#pragma unroll
    for (int ks = 0; ks < 4; ++ks) {
      bf16x8 a3[2], b3[4];
#pragma unroll
      for (int mi = 0; mi < 2; ++mi) {
        int row = wm + mi * 16 + lrow;
        int p = (ks * 4 + quad) ^ (row & 7);
        a3[mi] = *(const bf16x8*)(zbuf + row * 128 + p * 8);
      }
#pragma unroll
      for (int ni = 0; ni < 4; ++ni) {
        int row = wn + ni * 16 + lrow;
        int p = (ks * 4 + quad) ^ (row & 7);
        b3[ni] = *(const bf16x8*)(lB3 + row * 128 + p * 8);
      }
#pragma unroll
      for (int mi = 0; mi < 2; ++mi)
#pragma unroll
        for (int ni = 0; ni < 4; ++ni)
          out_acc[mi][ni] =
              __builtin_amdgcn_mfma_f32_16x16x32_bf16(a3[mi], b3[ni], out_acc[mi][ni], 0, 0, 0);
    }
    __syncthreads();  // zbuf/lB3 reads done before next chunk's overwrites
  }

  // epilogue: out = out_acc + b2
#pragma unroll
  for (int mi = 0; mi < 2; ++mi) {
#pragma unroll
    for (int ni = 0; ni < 4; ++ni) {
      int col = wn + ni * 16 + lrow;
      float bv = b2[col];
#pragma unroll
      for (int r = 0; r < 4; ++r) {
        int row = m0 + wm + mi * 16 + quad * 4 + r;
        out[(size_t)row * LABELS + col] = out_acc[mi][ni][r] + bv;
      }
    }
  }
}

// ---- launcher --------------------------------------------------------------

extern "C" void kernel_launch(void* const* d_in, const int* in_sizes, int n_in,
                              void* d_out, int out_size, void* d_ws, size_t ws_size,
                              hipStream_t stream) {
  const int* tok = (const int*)d_in[0];
  const float* emb = (const float*)d_in[1];
  const float* conv_w = (const float*)d_in[2];  // [512,512] = [N,K]
  const float* conv_b = (const float*)d_in[3];
  const float* w1 = (const float*)d_in[4];      // [512,1024] = [K,N]
  const float* b1 = (const float*)d_in[5];
  const float* w2 = (const float*)d_in[6];      // [1024,128] = [K,N]
  const float* b2 = (const float*)d_in[7];
  float* out = (float*)d_out;

  char* ws = (char*)d_ws;
  bf16* wtc = (bf16*)(ws);                       // 512 KB [512,512]
  bf16* wt1 = (bf16*)(ws + (1u << 19));          // 1 MB   [1024,512]
  bf16* wt2 = (bf16*)(ws + 3 * (1u << 19));      // 256 KB [128,1024]
  bf16* h = (bf16*)(ws + (2u << 20));            // 32 MB  [32768,512]

  // weight prep
  hipLaunchKernelGGL(cvt_bf16, dim3(256), dim3(256), 0, stream,
                     conv_w, wtc, CONV_C * EMBED);
  hipLaunchKernelGGL(transpose_cvt, dim3(8, 16), dim3(256), 0, stream,
                     w1, wt1, CONV_C, HID);
  hipLaunchKernelGGL(transpose_cvt, dim3(16, 2), dim3(256), 0, stream,
                     w2, wt2, HID, LABELS);

  // layer 1 (gather fused, XCD-grouped 1-D grid)
  hipLaunchKernelGGL(gemm1_gather, dim3(1024), dim3(256),
                     0, stream, tok, emb, wtc, conv_b, h, NROWS, CONV_C, EMBED);
  // layers 2+3 fused
  hipLaunchKernelGGL(gemm23_fused, dim3(NROWS / 64), dim3(256),
                     0, stream, h, wt1, wt2, b1, b2, out);
}

// Round 5
// 261.492 us; speedup vs baseline: 1.1055x; 1.1055x over previous
//
#include <hip/hip_runtime.h>

typedef __bf16 bf16;
typedef __bf16 bf16x4 __attribute__((ext_vector_type(4)));
typedef __bf16 bf16x8 __attribute__((ext_vector_type(8)));
typedef float f32x4 __attribute__((ext_vector_type(4)));

#define NROWS 32768   // B*S = 32*1024
#define EMBED 512
#define CONV_C 512
#define HID 1024
#define LABELS 128

__device__ inline void async16(const void* g, void* l) {
  __builtin_amdgcn_global_load_lds(
      (const __attribute__((address_space(1))) void*)g,
      (__attribute__((address_space(3))) void*)l, 16, 0, 0);
}

// swap low/high half-nibbles of a 4-bit value
__device__ inline int swap4(int x) { return ((x >> 2) | ((x & 3) << 2)) & 15; }
// swap bits 0 and 2 of a 4-bit value (involution)
__device__ inline int bitswap02(int g) {
  return ((g & 1) << 2) | (g & 0xA) | ((g >> 2) & 1);
}

// two 16B fp32 chunks (swizzled positions) -> bf16x8 fragment
__device__ inline bf16x8 cvt8_sw(const float* row, int o0, int o1) {
  f32x4 lo = *(const f32x4*)(row + o0);
  f32x4 hi = *(const f32x4*)(row + o1);
  bf16x8 r;
  r[0] = (bf16)lo[0]; r[1] = (bf16)lo[1]; r[2] = (bf16)lo[2]; r[3] = (bf16)lo[3];
  r[4] = (bf16)hi[0]; r[5] = (bf16)hi[1]; r[6] = (bf16)hi[2]; r[7] = (bf16)hi[3];
  return r;
}

// ---- prep kernels ----------------------------------------------------------

__global__ void cvt_bf16(const float* __restrict__ in, bf16* __restrict__ out, int n) {
  int i = (blockIdx.x * blockDim.x + threadIdx.x) * 4;
  if (i >= n) return;
  float4 v = *(const float4*)(in + i);
  bf16x4 o;
  o.x = (bf16)v.x; o.y = (bf16)v.y; o.z = (bf16)v.z; o.w = (bf16)v.w;
  *(bf16x4*)(out + i) = o;
}

// [K,N] f32 -> [N,K] bf16 transpose, 64x64 tiles
__global__ void transpose_cvt(const float* __restrict__ in, bf16* __restrict__ out,
                              int K, int N) {
  __shared__ float t[64][65];
  int kb = blockIdx.x * 64, nb = blockIdx.y * 64;
  for (int i = threadIdx.x; i < 4096; i += 256) {
    int r = i >> 6, c = i & 63;
    t[r][c] = in[(size_t)(kb + r) * N + nb + c];
  }
  __syncthreads();
  for (int i = threadIdx.x; i < 4096; i += 256) {
    int r = i >> 6, c = i & 63;
    out[(size_t)(nb + r) * K + kb + c] = (bf16)t[c][r];
  }
}

// ---- layer 1: h = relu(emb[tok] @ conv_w^T + conv_b), gather fused ---------
// (R3 version: 2-D grid, fp32 A staged with 16B-granule XOR swizzle)
__global__ __launch_bounds__(256) void gemm1_gather(
    const int* __restrict__ tok, const float* __restrict__ emb,
    const bf16* __restrict__ convw, const float* __restrict__ bias,
    bf16* __restrict__ out, int M, int N, int K) {
  __shared__ __attribute__((aligned(16))) float lAf[128 * 32];  // 16 KB
  __shared__ __attribute__((aligned(16))) bf16 lB[128 * 32];    //  8 KB
  const int tid = threadIdx.x;
  const int wave = tid >> 6, lane = tid & 63;
  const int m0 = blockIdx.x * 128, n0 = blockIdx.y * 128;
  const int wm = (wave & 1) * 64, wn = (wave >> 1) * 64;
  const int lrow = lane & 15, quad = lane >> 4;
  const int slot0 = wave * 64 + lane;

  int arow[4], acol[4];
#pragma unroll
  for (int c = 0; c < 4; ++c) {
    int s = slot0 + c * 256;
    int r = s >> 3, p = s & 7;
    arow[c] = r;
    acol[c] = (p ^ (r & 7)) * 4;
  }
  int trow[4];
#pragma unroll
  for (int c = 0; c < 4; ++c) trow[c] = tok[m0 + arow[c]];

  const f32x4 zero4 = {0.f, 0.f, 0.f, 0.f};
  f32x4 acc[4][4];
#pragma unroll
  for (int i = 0; i < 4; ++i)
#pragma unroll
    for (int j = 0; j < 4; ++j) acc[i][j] = zero4;

  for (int k0 = 0; k0 < K; k0 += 32) {
#pragma unroll
    for (int c = 0; c < 4; ++c)
      async16(emb + (size_t)trow[c] * EMBED + k0 + acol[c],
              lAf + (size_t)(wave * 64 + c * 256) * 4);
#pragma unroll
    for (int c = 0; c < 2; ++c) {
      int s = slot0 + c * 256;
      int r = s >> 2, cs = s & 3;
      async16(convw + (size_t)(n0 + r) * K + k0 + cs * 8,
              lB + (size_t)(wave * 64 + c * 256) * 8);
    }
    __syncthreads();

    bf16x8 a[4], b[4];
#pragma unroll
    for (int t = 0; t < 4; ++t) {
      int r = wm + t * 16 + lrow, sw = r & 7;
      a[t] = cvt8_sw(lAf + r * 32, ((2 * quad) ^ sw) * 4, ((2 * quad + 1) ^ sw) * 4);
      b[t] = *(const bf16x8*)(lB + (wn + t * 16 + lrow) * 32 + quad * 8);
    }
#pragma unroll
    for (int mi = 0; mi < 4; ++mi)
#pragma unroll
      for (int ni = 0; ni < 4; ++ni)
        acc[mi][ni] =
            __builtin_amdgcn_mfma_f32_16x16x32_bf16(a[mi], b[ni], acc[mi][ni], 0, 0, 0);
    __syncthreads();
  }

#pragma unroll
  for (int mi = 0; mi < 4; ++mi) {
#pragma unroll
    for (int ni = 0; ni < 4; ++ni) {
      int col = n0 + wn + ni * 16 + lrow;
      float bv = bias[col];
#pragma unroll
      for (int r = 0; r < 4; ++r) {
        int row = m0 + wm + mi * 16 + quad * 4 + r;
        float v = acc[mi][ni][r] + bv;
        v = v > 0.f ? v : 0.f;
        out[(size_t)row * N + col] = (bf16)v;
      }
    }
  }
}

// ---- fused layers 2+3 (v2: BK=64 + conflict-free swizzles) -----------------
// zbuf/lB3 element (row, col): g = col>>3, pos = bitswap02(g) ^ swap4(row&15)
// lA/lB  element (row, col): g = col>>3, pos = g ^ (row&7)
__global__ __launch_bounds__(256) void gemm23_fused(
    const bf16* __restrict__ h,     // [32768, 512]
    const bf16* __restrict__ w1t,   // [1024, 512]
    const bf16* __restrict__ w2t,   // [128, 1024]
    const float* __restrict__ b1, const float* __restrict__ b2,
    float* __restrict__ out) {
  __shared__ __attribute__((aligned(16))) bf16 lA[64 * 64];     //  8 KB
  __shared__ __attribute__((aligned(16))) bf16 lB[128 * 64];    // 16 KB
  __shared__ __attribute__((aligned(16))) bf16 zbuf[64 * 128];  // 16 KB
  __shared__ __attribute__((aligned(16))) bf16 lB3[128 * 128];  // 32 KB
  const int tid = threadIdx.x, wave = tid >> 6, lane = tid & 63;
  const int m0 = blockIdx.x * 64;
  const int wm = (wave & 1) * 32, wn = (wave >> 1) * 64;
  const int lrow = lane & 15, quad = lane >> 4;
  const int slot0 = wave * 64 + lane;
  const int sw_lrow = swap4(lrow);

  // staging geometry: lA 512 granule-slots (64r x 8), lB 1024 (128r x 8)
  int a_r[2], a_c[2];
#pragma unroll
  for (int c = 0; c < 2; ++c) {
    int s = slot0 + c * 256;
    a_r[c] = s >> 3;
    a_c[c] = ((s & 7) ^ (a_r[c] & 7)) * 8;
  }
  int b_r[4], b_c[4];
#pragma unroll
  for (int c = 0; c < 4; ++c) {
    int s = slot0 + c * 256;
    b_r[c] = s >> 3;
    b_c[c] = ((s & 7) ^ (b_r[c] & 7)) * 8;
  }
  // lB3 staging: 2048 slots (128r x 16), 8 issues
  int w2_r[8], w2_c[8];
#pragma unroll
  for (int c = 0; c < 8; ++c) {
    int s = slot0 + c * 256;
    w2_r[c] = s >> 4;
    w2_c[c] = bitswap02((s & 15) ^ swap4(w2_r[c] & 15)) * 8;
  }

  const f32x4 zero4 = {0.f, 0.f, 0.f, 0.f};
  f32x4 out_acc[2][4];
#pragma unroll
  for (int i = 0; i < 2; ++i)
#pragma unroll
    for (int j = 0; j < 4; ++j) out_acc[i][j] = zero4;

  for (int chunk = 0; chunk < 8; ++chunk) {
    f32x4 z_acc[2][4];
#pragma unroll
    for (int i = 0; i < 2; ++i)
#pragma unroll
      for (int j = 0; j < 4; ++j) z_acc[i][j] = zero4;

    const bf16* wB = w1t + (size_t)(chunk * 128) * 512;
    for (int k0 = 0; k0 < 512; k0 += 64) {
#pragma unroll
      for (int c = 0; c < 2; ++c)
        async16(h + (size_t)(m0 + a_r[c]) * 512 + k0 + a_c[c],
                lA + (size_t)(wave * 64 + c * 256) * 8);
#pragma unroll
      for (int c = 0; c < 4; ++c)
        async16(wB + (size_t)b_r[c] * 512 + k0 + b_c[c],
                lB + (size_t)(wave * 64 + c * 256) * 8);
      __syncthreads();

#pragma unroll
      for (int ks = 0; ks < 2; ++ks) {
        bf16x8 a[2], b[4];
#pragma unroll
        for (int t = 0; t < 2; ++t) {
          int row = wm + t * 16 + lrow;
          int pos = (ks * 4 + quad) ^ (row & 7);
          a[t] = *(const bf16x8*)(lA + row * 64 + pos * 8);
        }
#pragma unroll
        for (int t = 0; t < 4; ++t) {
          int row = wn + t * 16 + lrow;
          int pos = (ks * 4 + quad) ^ (row & 7);
          b[t] = *(const bf16x8*)(lB + row * 64 + pos * 8);
        }
#pragma unroll
        for (int mi = 0; mi < 2; ++mi)
#pragma unroll
          for (int ni = 0; ni < 4; ++ni)
            z_acc[mi][ni] =
                __builtin_amdgcn_mfma_f32_16x16x32_bf16(a[mi], b[ni], z_acc[mi][ni], 0, 0, 0);
      }
      __syncthreads();
    }

    // stage w2t chunk into lB3 (swizzled)
#pragma unroll
    for (int c = 0; c < 8; ++c)
      async16(w2t + (size_t)w2_r[c] * HID + chunk * 128 + w2_c[c],
              lB3 + (size_t)(wave * 64 + c * 256) * 8);

    // write z (bias+relu, bf16) into swizzled zbuf
#pragma unroll
    for (int mi = 0; mi < 2; ++mi) {
#pragma unroll
      for (int ni = 0; ni < 4; ++ni) {
        int col = wn + ni * 16 + lrow;
        float bv = b1[chunk * 128 + col];
        int gsw = bitswap02(col >> 3);
#pragma unroll
        for (int r = 0; r < 4; ++r) {
          int row = wm + mi * 16 + quad * 4 + r;
          float v = z_acc[mi][ni][r] + bv;
          v = v > 0.f ? v : 0.f;
          int pos = gsw ^ (quad | (r << 2));  // swap4(quad*4+r) = quad | r<<2
          zbuf[row * 128 + pos * 8 + (col & 7)] = (bf16)v;
        }
      }
    }
    __syncthreads();

    // layer 3: out_acc += z_chunk @ w2t_chunk^T (K=128)
#pragma unroll
    for (int ks = 0; ks < 4; ++ks) {
      int possw = bitswap02(ks * 4 + quad) ^ sw_lrow;
      bf16x8 a3[2], b3[4];
#pragma unroll
      for (int mi = 0; mi < 2; ++mi) {
        int row = wm + mi * 16 + lrow;
        a3[mi] = *(const bf16x8*)(zbuf + row * 128 + possw * 8);
      }
#pragma unroll
      for (int ni = 0; ni < 4; ++ni) {
        int row = wn + ni * 16 + lrow;
        b3[ni] = *(const bf16x8*)(lB3 + row * 128 + possw * 8);
      }
#pragma unroll
      for (int mi = 0; mi < 2; ++mi)
#pragma unroll
        for (int ni = 0; ni < 4; ++ni)
          out_acc[mi][ni] =
              __builtin_amdgcn_mfma_f32_16x16x32_bf16(a3[mi], b3[ni], out_acc[mi][ni], 0, 0, 0);
    }
    __syncthreads();
  }

  // epilogue: out = out_acc + b2
#pragma unroll
  for (int mi = 0; mi < 2; ++mi) {
#pragma unroll
    for (int ni = 0; ni < 4; ++ni) {
      int col = wn + ni * 16 + lrow;
      float bv = b2[col];
#pragma unroll
      for (int r = 0; r < 4; ++r) {
        int row = m0 + wm + mi * 16 + quad * 4 + r;
        out[(size_t)row * LABELS + col] = out_acc[mi][ni][r] + bv;
      }
    }
  }
}

// ---- launcher --------------------------------------------------------------

extern "C" void kernel_launch(void* const* d_in, const int* in_sizes, int n_in,
                              void* d_out, int out_size, void* d_ws, size_t ws_size,
                              hipStream_t stream) {
  const int* tok = (const int*)d_in[0];
  const float* emb = (const float*)d_in[1];
  const float* conv_w = (const float*)d_in[2];  // [512,512] = [N,K]
  const float* conv_b = (const float*)d_in[3];
  const float* w1 = (const float*)d_in[4];      // [512,1024] = [K,N]
  const float* b1 = (const float*)d_in[5];
  const float* w2 = (const float*)d_in[6];      // [1024,128] = [K,N]
  const float* b2 = (const float*)d_in[7];
  float* out = (float*)d_out;

  char* ws = (char*)d_ws;
  bf16* wtc = (bf16*)(ws);                       // 512 KB [512,512]
  bf16* wt1 = (bf16*)(ws + (1u << 19));          // 1 MB   [1024,512]
  bf16* wt2 = (bf16*)(ws + 3 * (1u << 19));      // 256 KB [128,1024]
  bf16* h = (bf16*)(ws + (2u << 20));            // 32 MB  [32768,512]

  // weight prep
  hipLaunchKernelGGL(cvt_bf16, dim3(256), dim3(256), 0, stream,
                     conv_w, wtc, CONV_C * EMBED);
  hipLaunchKernelGGL(transpose_cvt, dim3(8, 16), dim3(256), 0, stream,
                     w1, wt1, CONV_C, HID);
  hipLaunchKernelGGL(transpose_cvt, dim3(16, 2), dim3(256), 0, stream,
                     w2, wt2, HID, LABELS);

  // layer 1 (gather fused, 2-D grid as in R3)
  hipLaunchKernelGGL(gemm1_gather, dim3(NROWS / 128, CONV_C / 128), dim3(256),
                     0, stream, tok, emb, wtc, conv_b, h, NROWS, CONV_C, EMBED);
  // layers 2+3 fused
  hipLaunchKernelGGL(gemm23_fused, dim3(NROWS / 64), dim3(256),
                     0, stream, h, wt1, wt2, b1, b2, out);
}

// Round 6
// 254.838 us; speedup vs baseline: 1.1344x; 1.0261x over previous
//
#include <hip/hip_runtime.h>

typedef __bf16 bf16;
typedef __bf16 bf16x4 __attribute__((ext_vector_type(4)));
typedef __bf16 bf16x8 __attribute__((ext_vector_type(8)));
typedef float f32x4 __attribute__((ext_vector_type(4)));

#define NROWS 32768   // B*S = 32*1024
#define EMBED 512
#define CONV_C 512
#define HID 1024
#define LABELS 128

__device__ inline void async16(const void* g, void* l) {
  __builtin_amdgcn_global_load_lds(
      (const __attribute__((address_space(1))) void*)g,
      (__attribute__((address_space(3))) void*)l, 16, 0, 0);
}

// swap low/high half-nibbles of a 4-bit value
__device__ inline int swap4(int x) { return ((x >> 2) | ((x & 3) << 2)) & 15; }
// swap bits 0 and 2 of a 4-bit value (involution)
__device__ inline int bitswap02(int g) {
  return ((g & 1) << 2) | (g & 0xA) | ((g >> 2) & 1);
}

// two 16B fp32 chunks (swizzled positions) -> bf16x8 fragment
__device__ inline bf16x8 cvt8_sw(const float* row, int o0, int o1) {
  f32x4 lo = *(const f32x4*)(row + o0);
  f32x4 hi = *(const f32x4*)(row + o1);
  bf16x8 r;
  r[0] = (bf16)lo[0]; r[1] = (bf16)lo[1]; r[2] = (bf16)lo[2]; r[3] = (bf16)lo[3];
  r[4] = (bf16)hi[0]; r[5] = (bf16)hi[1]; r[6] = (bf16)hi[2]; r[7] = (bf16)hi[3];
  return r;
}

// ---- prep kernels ----------------------------------------------------------

__global__ void cvt_bf16(const float* __restrict__ in, bf16* __restrict__ out, int n) {
  int i = (blockIdx.x * blockDim.x + threadIdx.x) * 4;
  if (i >= n) return;
  float4 v = *(const float4*)(in + i);
  bf16x4 o;
  o.x = (bf16)v.x; o.y = (bf16)v.y; o.z = (bf16)v.z; o.w = (bf16)v.w;
  *(bf16x4*)(out + i) = o;
}

// [K,N] f32 -> [N,K] bf16 transpose, 64x64 tiles
__global__ void transpose_cvt(const float* __restrict__ in, bf16* __restrict__ out,
                              int K, int N) {
  __shared__ float t[64][65];
  int kb = blockIdx.x * 64, nb = blockIdx.y * 64;
  for (int i = threadIdx.x; i < 4096; i += 256) {
    int r = i >> 6, c = i & 63;
    t[r][c] = in[(size_t)(kb + r) * N + nb + c];
  }
  __syncthreads();
  for (int i = threadIdx.x; i < 4096; i += 256) {
    int r = i >> 6, c = i & 63;
    out[(size_t)(nb + r) * K + kb + c] = (bf16)t[c][r];
  }
}

// ---- layer 1: h = relu(emb[tok] @ conv_w^T + conv_b) -----------------------
// gather fused; double-buffered staging, ONE barrier per K-iter.
// buf = [lAf fp32 128x32 (16KB) | lB bf16 128x32 (8KB)] x2 = 48 KB -> 3 blk/CU
__global__ __launch_bounds__(256) void gemm1_gather(
    const int* __restrict__ tok, const float* __restrict__ emb,
    const bf16* __restrict__ convw, const float* __restrict__ bias,
    bf16* __restrict__ out, int M, int N, int K) {
  __shared__ __attribute__((aligned(16))) char smem[49152];
  const int tid = threadIdx.x;
  const int wave = tid >> 6, lane = tid & 63;
  const int m0 = blockIdx.x * 128, n0 = blockIdx.y * 128;
  const int wm = (wave & 1) * 64, wn = (wave >> 1) * 64;
  const int lrow = lane & 15, quad = lane >> 4;
  const int slot0 = wave * 64 + lane;

  int arow[4], acol[4];
#pragma unroll
  for (int c = 0; c < 4; ++c) {
    int s = slot0 + c * 256;
    int r = s >> 3, p = s & 7;
    arow[c] = r;
    acol[c] = (p ^ (r & 7)) * 4;
  }
  int trow[4];
#pragma unroll
  for (int c = 0; c < 4; ++c) trow[c] = tok[m0 + arow[c]];

  const f32x4 zero4 = {0.f, 0.f, 0.f, 0.f};
  f32x4 acc[4][4];
#pragma unroll
  for (int i = 0; i < 4; ++i)
#pragma unroll
    for (int j = 0; j < 4; ++j) acc[i][j] = zero4;

  auto stage = [&](int p, int k0) {
    float* lAf = (float*)(smem + p * 24576);
    bf16* lB = (bf16*)(smem + p * 24576 + 16384);
#pragma unroll
    for (int c = 0; c < 4; ++c)
      async16(emb + (size_t)trow[c] * EMBED + k0 + acol[c],
              lAf + (size_t)(wave * 64 + c * 256) * 4);
#pragma unroll
    for (int c = 0; c < 2; ++c) {
      int s = slot0 + c * 256;
      int r = s >> 2, cs = s & 3;
      async16(convw + (size_t)(n0 + r) * K + k0 + cs * 8,
              lB + (size_t)(wave * 64 + c * 256) * 8);
    }
  };

  stage(0, 0);
  int cur = 0;
  for (int it = 0; it < 16; ++it) {
    __syncthreads();                       // buf[cur] staged; prior reads fenced
    if (it < 15) stage(cur ^ 1, (it + 1) * 32);
    const float* lAf = (const float*)(smem + cur * 24576);
    const bf16* lB = (const bf16*)(smem + cur * 24576 + 16384);

    bf16x8 a[4], b[4];
#pragma unroll
    for (int t = 0; t < 4; ++t) {
      int r = wm + t * 16 + lrow, sw = r & 7;
      a[t] = cvt8_sw(lAf + r * 32, ((2 * quad) ^ sw) * 4, ((2 * quad + 1) ^ sw) * 4);
      b[t] = *(const bf16x8*)(lB + (wn + t * 16 + lrow) * 32 + quad * 8);
    }
#pragma unroll
    for (int mi = 0; mi < 4; ++mi)
#pragma unroll
      for (int ni = 0; ni < 4; ++ni)
        acc[mi][ni] =
            __builtin_amdgcn_mfma_f32_16x16x32_bf16(a[mi], b[ni], acc[mi][ni], 0, 0, 0);
    cur ^= 1;
  }

#pragma unroll
  for (int mi = 0; mi < 4; ++mi) {
#pragma unroll
    for (int ni = 0; ni < 4; ++ni) {
      int col = n0 + wn + ni * 16 + lrow;
      float bv = bias[col];
#pragma unroll
      for (int r = 0; r < 4; ++r) {
        int row = m0 + wm + mi * 16 + quad * 4 + r;
        float v = acc[mi][ni][r] + bv;
        v = v > 0.f ? v : 0.f;
        out[(size_t)row * N + col] = (bf16)v;
      }
    }
  }
}

// ---- fused layers 2+3 (v3: double-buffered staging, 1 barrier/iter) --------
// LDS map (80 KB total -> 2 blocks/CU):
//   [0, 24576)      buf0 = lA0 (64x64 bf16, 8KB) + lB0 (128x64 bf16, 16KB)
//                   zbuf (64x128 bf16, 16KB) ALIASES buf0 (dead by z-write)
//   [24576, 49152)  buf1 = lA1 + lB1
//   [49152, 81920)  lB3  (128x128 bf16, 32KB), staged at chunk start
__global__ __launch_bounds__(256) void gemm23_fused(
    const bf16* __restrict__ h,     // [32768, 512]
    const bf16* __restrict__ w1t,   // [1024, 512]
    const bf16* __restrict__ w2t,   // [128, 1024]
    const float* __restrict__ b1, const float* __restrict__ b2,
    float* __restrict__ out) {
  __shared__ __attribute__((aligned(16))) char smem[81920];
  bf16* zbuf = (bf16*)smem;
  bf16* lB3 = (bf16*)(smem + 49152);
  const int tid = threadIdx.x, wave = tid >> 6, lane = tid & 63;
  const int m0 = blockIdx.x * 64;
  const int wm = (wave & 1) * 32, wn = (wave >> 1) * 64;
  const int lrow = lane & 15, quad = lane >> 4;
  const int slot0 = wave * 64 + lane;
  const int sw_lrow = swap4(lrow);

  // staging geometry
  int a_r[2], a_c[2];
#pragma unroll
  for (int c = 0; c < 2; ++c) {
    int s = slot0 + c * 256;
    a_r[c] = s >> 3;
    a_c[c] = ((s & 7) ^ (a_r[c] & 7)) * 8;
  }
  int b_r[4], b_c[4];
#pragma unroll
  for (int c = 0; c < 4; ++c) {
    int s = slot0 + c * 256;
    b_r[c] = s >> 3;
    b_c[c] = ((s & 7) ^ (b_r[c] & 7)) * 8;
  }
  int w2_r[8], w2_c[8];
#pragma unroll
  for (int c = 0; c < 8; ++c) {
    int s = slot0 + c * 256;
    w2_r[c] = s >> 4;
    w2_c[c] = bitswap02((s & 15) ^ swap4(w2_r[c] & 15)) * 8;
  }

  auto stage = [&](int p, const bf16* wB, int k0) {
    bf16* lA = (bf16*)(smem + p * 24576);
    bf16* lB = (bf16*)(smem + p * 24576 + 8192);
#pragma unroll
    for (int c = 0; c < 2; ++c)
      async16(h + (size_t)(m0 + a_r[c]) * 512 + k0 + a_c[c],
              lA + (size_t)(wave * 64 + c * 256) * 8);
#pragma unroll
    for (int c = 0; c < 4; ++c)
      async16(wB + (size_t)b_r[c] * 512 + k0 + b_c[c],
              lB + (size_t)(wave * 64 + c * 256) * 8);
  };

  const f32x4 zero4 = {0.f, 0.f, 0.f, 0.f};
  f32x4 out_acc[2][4];
#pragma unroll
  for (int i = 0; i < 2; ++i)
#pragma unroll
    for (int j = 0; j < 4; ++j) out_acc[i][j] = zero4;

  for (int chunk = 0; chunk < 8; ++chunk) {
    f32x4 z_acc[2][4];
#pragma unroll
    for (int i = 0; i < 2; ++i)
#pragma unroll
      for (int j = 0; j < 4; ++j) z_acc[i][j] = zero4;

    const bf16* wB = w1t + (size_t)(chunk * 128) * 512;

    // lB3 staging hidden under the whole k-loop
#pragma unroll
    for (int c = 0; c < 8; ++c)
      async16(w2t + (size_t)w2_r[c] * HID + chunk * 128 + w2_c[c],
              lB3 + (size_t)(wave * 64 + c * 256) * 8);
    stage(0, wB, 0);

    int cur = 0;
    for (int it = 0; it < 8; ++it) {
      __syncthreads();                    // buf[cur] landed; prior reads fenced
      if (it < 7) stage(cur ^ 1, wB, (it + 1) * 64);
      const bf16* lA = (const bf16*)(smem + cur * 24576);
      const bf16* lB = (const bf16*)(smem + cur * 24576 + 8192);

#pragma unroll
      for (int ks = 0; ks < 2; ++ks) {
        bf16x8 a[2], b[4];
#pragma unroll
        for (int t = 0; t < 2; ++t) {
          int row = wm + t * 16 + lrow;
          int pos = (ks * 4 + quad) ^ (row & 7);
          a[t] = *(const bf16x8*)(lA + row * 64 + pos * 8);
        }
#pragma unroll
        for (int t = 0; t < 4; ++t) {
          int row = wn + t * 16 + lrow;
          int pos = (ks * 4 + quad) ^ (row & 7);
          b[t] = *(const bf16x8*)(lB + row * 64 + pos * 8);
        }
#pragma unroll
        for (int mi = 0; mi < 2; ++mi)
#pragma unroll
          for (int ni = 0; ni < 4; ++ni)
            z_acc[mi][ni] =
                __builtin_amdgcn_mfma_f32_16x16x32_bf16(a[mi], b[ni], z_acc[mi][ni], 0, 0, 0);
      }
      cur ^= 1;
    }
    // buf0 reads all fenced by iter-7 barrier; zbuf (alias of buf0) now safe.
    // write z (bias+relu, bf16) into swizzled zbuf
#pragma unroll
    for (int mi = 0; mi < 2; ++mi) {
#pragma unroll
      for (int ni = 0; ni < 4; ++ni) {
        int col = wn + ni * 16 + lrow;
        float bv = b1[chunk * 128 + col];
        int gsw = bitswap02(col >> 3);
#pragma unroll
        for (int r = 0; r < 4; ++r) {
          int row = wm + mi * 16 + quad * 4 + r;
          float v = z_acc[mi][ni][r] + bv;
          v = v > 0.f ? v : 0.f;
          int pos = gsw ^ (quad | (r << 2));  // swap4(quad*4+r)
          zbuf[row * 128 + pos * 8 + (col & 7)] = (bf16)v;
        }
      }
    }
    __syncthreads();   // zbuf visible to all waves (lB3 long since drained)

    // layer 3: out_acc += z_chunk @ w2t_chunk^T (K=128)
#pragma unroll
    for (int ks = 0; ks < 4; ++ks) {
      int possw = bitswap02(ks * 4 + quad) ^ sw_lrow;
      bf16x8 a3[2], b3[4];
#pragma unroll
      for (int mi = 0; mi < 2; ++mi) {
        int row = wm + mi * 16 + lrow;
        a3[mi] = *(const bf16x8*)(zbuf + row * 128 + possw * 8);
      }
#pragma unroll
      for (int ni = 0; ni < 4; ++ni) {
        int row = wn + ni * 16 + lrow;
        b3[ni] = *(const bf16x8*)(lB3 + row * 128 + possw * 8);
      }
#pragma unroll
      for (int mi = 0; mi < 2; ++mi)
#pragma unroll
        for (int ni = 0; ni < 4; ++ni)
          out_acc[mi][ni] =
              __builtin_amdgcn_mfma_f32_16x16x32_bf16(a3[mi], b3[ni], out_acc[mi][ni], 0, 0, 0);
    }
    __syncthreads();   // zbuf/lB3 reads done before next chunk's staging
  }

  // epilogue: out = out_acc + b2
#pragma unroll
  for (int mi = 0; mi < 2; ++mi) {
#pragma unroll
    for (int ni = 0; ni < 4; ++ni) {
      int col = wn + ni * 16 + lrow;
      float bv = b2[col];
#pragma unroll
      for (int r = 0; r < 4; ++r) {
        int row = m0 + wm + mi * 16 + quad * 4 + r;
        out[(size_t)row * LABELS + col] = out_acc[mi][ni][r] + bv;
      }
    }
  }
}

// ---- launcher --------------------------------------------------------------

extern "C" void kernel_launch(void* const* d_in, const int* in_sizes, int n_in,
                              void* d_out, int out_size, void* d_ws, size_t ws_size,
                              hipStream_t stream) {
  const int* tok = (const int*)d_in[0];
  const float* emb = (const float*)d_in[1];
  const float* conv_w = (const float*)d_in[2];  // [512,512] = [N,K]
  const float* conv_b = (const float*)d_in[3];
  const float* w1 = (const float*)d_in[4];      // [512,1024] = [K,N]
  const float* b1 = (const float*)d_in[5];
  const float* w2 = (const float*)d_in[6];      // [1024,128] = [K,N]
  const float* b2 = (const float*)d_in[7];
  float* out = (float*)d_out;

  char* ws = (char*)d_ws;
  bf16* wtc = (bf16*)(ws);                       // 512 KB [512,512]
  bf16* wt1 = (bf16*)(ws + (1u << 19));          // 1 MB   [1024,512]
  bf16* wt2 = (bf16*)(ws + 3 * (1u << 19));      // 256 KB [128,1024]
  bf16* h = (bf16*)(ws + (2u << 20));            // 32 MB  [32768,512]

  // weight prep
  hipLaunchKernelGGL(cvt_bf16, dim3(256), dim3(256), 0, stream,
                     conv_w, wtc, CONV_C * EMBED);
  hipLaunchKernelGGL(transpose_cvt, dim3(8, 16), dim3(256), 0, stream,
                     w1, wt1, CONV_C, HID);
  hipLaunchKernelGGL(transpose_cvt, dim3(16, 2), dim3(256), 0, stream,
                     w2, wt2, HID, LABELS);

  // layer 1 (gather fused, double-buffered)
  hipLaunchKernelGGL(gemm1_gather, dim3(NROWS / 128, CONV_C / 128), dim3(256),
                     0, stream, tok, emb, wtc, conv_b, h, NROWS, CONV_C, EMBED);
  // layers 2+3 fused (double-buffered)
  hipLaunchKernelGGL(gemm23_fused, dim3(NROWS / 64), dim3(256),
                     0, stream, h, wt1, wt2, b1, b2, out);
}